// Round 13
// baseline (163.643 us; speedup 1.0000x reference)
//
#include <hip/hip_runtime.h>
#include <hip/hip_bf16.h>
#include <math.h>

// Problem constants (fixed by the reference)
#define BB   8
#define NQ   256
#define NKV  1024
#define DD   256   // DQ == DK == DV == 256
#define HH   128   // hidden
#define KSPLIT 8   // k-splits per q-tile (finer items -> queue balance)
#define KCH  128   // k per split (NKV / KSPLIT)
#define NITEMS (BB * (NQ / 8) * KSPLIT)   // 2048 work items
#define NWORK  512                        // persistent worker blocks (2/CU)

typedef float f16v __attribute__((ext_vector_type(16)));

// ---------------------------------------------------------------------------
// Kernel 1: fused projection + exp.  (unchanged)
// ---------------------------------------------------------------------------
__global__ __launch_bounds__(256) void proj_exp_kernel(
    const float* __restrict__ Q, const float* __restrict__ K,
    const float* __restrict__ Wq, const float* __restrict__ Wk,
    float* __restrict__ eqb, float* __restrict__ ekb)
{
    __shared__ __align__(16) float At[32][20];   // [d][row], 16 rows used
    __shared__ __align__(16) float Wt[32][132];  // [d][h], pad to 132

    const int bid = blockIdx.x;
    const bool isQ = bid < (BB * NQ / 16);       // first 128 blocks: Q part
    const float* A = isQ ? Q : K;
    const float* W = isQ ? Wq : Wk;
    float* Out     = isQ ? eqb : ekb;
    const int arow0 = (isQ ? bid : bid - (BB * NQ / 16)) * 16;

    const int tid = threadIdx.x;
    const int rc  = tid >> 5;    // rows rc and rc+8
    const int hc  = tid & 31;    // h-quad: h = hc*4..hc*4+3

    float4 c0 = {0.f,0.f,0.f,0.f}, c1 = c0;

    float4 a4;
    float4 w4[4];

    if (tid < 128)
        a4 = *(const float4*)(A + (size_t)(arow0 + (tid >> 3)) * DD + (tid & 7) * 4);
#pragma unroll
    for (int t = 0; t < 4; ++t) {
        int idx = tid + t * 256;
        int h = idx >> 3, dw = idx & 7;
        w4[t] = *(const float4*)(W + (size_t)h * DD + dw * 4);
    }

    for (int ch = 0; ch < 8; ++ch) {
        __syncthreads();
        if (tid < 128) {
            int r_st = tid >> 3, dq = tid & 7;
            At[dq*4+0][r_st] = a4.x;
            At[dq*4+1][r_st] = a4.y;
            At[dq*4+2][r_st] = a4.z;
            At[dq*4+3][r_st] = a4.w;
        }
#pragma unroll
        for (int t = 0; t < 4; ++t) {
            int idx = tid + t * 256;
            int h = idx >> 3, dw = idx & 7;
            Wt[dw*4+0][h] = w4[t].x;
            Wt[dw*4+1][h] = w4[t].y;
            Wt[dw*4+2][h] = w4[t].z;
            Wt[dw*4+3][h] = w4[t].w;
        }
        __syncthreads();
        if (ch + 1 < 8) {
            const int dc = (ch + 1) * 32;
            if (tid < 128)
                a4 = *(const float4*)(A + (size_t)(arow0 + (tid >> 3)) * DD + dc + (tid & 7) * 4);
#pragma unroll
            for (int t = 0; t < 4; ++t) {
                int idx = tid + t * 256;
                int h = idx >> 3, dw = idx & 7;
                w4[t] = *(const float4*)(W + (size_t)h * DD + dc + dw * 4);
            }
        }
#pragma unroll
        for (int d = 0; d < 32; ++d) {
            float a0  = At[d][rc];
            float a1  = At[d][rc + 8];
            float4 wv = *(const float4*)&Wt[d][hc * 4];
            c0.x = fmaf(a0, wv.x, c0.x); c0.y = fmaf(a0, wv.y, c0.y);
            c0.z = fmaf(a0, wv.z, c0.z); c0.w = fmaf(a0, wv.w, c0.w);
            c1.x = fmaf(a1, wv.x, c1.x); c1.y = fmaf(a1, wv.y, c1.y);
            c1.z = fmaf(a1, wv.z, c1.z); c1.w = fmaf(a1, wv.w, c1.w);
        }
    }

    float4 o;
    float* p0 = Out + (size_t)(arow0 + rc) * HH + hc * 4;
    o.x = __expf(2.f*c0.x); o.y = __expf(2.f*c0.y);
    o.z = __expf(2.f*c0.z); o.w = __expf(2.f*c0.w);
    *(float4*)p0 = o;
    float* p1 = Out + (size_t)(arow0 + rc + 8) * HH + hc * 4;
    o.x = __expf(2.f*c1.x); o.y = __expf(2.f*c1.y);
    o.z = __expf(2.f*c1.z); o.w = __expf(2.f*c1.w);
    *(float4*)p1 = o;
}

// ---------------------------------------------------------------------------
// Kernel 2 v5.1: persistent partial attention, NO-MAX softmax + atomic merge.
// FIX vs v5 (round-12 fail, absmax 0.71): red's last dim is V-COLUMNS (DD),
// not k (KCH). v5 declared red[4][8][KCH=128] while the PV reduction writes
// red[w][r][lane*4+0..3] for lane<64 -> needs 256 floats/row; lanes >= 32
// smashed the next row. Worked in rounds 6-10 only because KCH==DD==256.
// ---------------------------------------------------------------------------
__global__ __launch_bounds__(512) void attn_partial_kernel(
    const float* __restrict__ V, const int* __restrict__ vls,
    const float* __restrict__ Wv,
    const float* __restrict__ eqb, const float* __restrict__ ekb,
    float* __restrict__ acc_out, float* __restrict__ lsum,
    unsigned int* __restrict__ qcnt)
{
    __shared__ __align__(16) float sc[8][KCH];        // exp(scores) (4 KB)
    __shared__ __align__(16) float red[4][8][DD];     // PV partials (32 KB)
    __shared__ int curs;

    const int tid  = threadIdx.x;
    const int w    = tid >> 6;          // wave 0..7
    const int lane = tid & 63;
    const int qg = w & 1;                            // q-group (rows qg*4..+3)
    const int ks = ((w >> 1) << 3) + (lane >> 3);    // 0..31 k-slot
    const int hg = lane & 7;                         // h-group (h = hg*16..+15)

    // Wv slice (item-invariant): nw2[j] = -2*Wv[hg*16+j]; swv = sum of own Wv
    f16v nw2;
    float swv = 0.f;
#pragma unroll
    for (int i = 0; i < 4; ++i) {
        float4 v4 = *(const float4*)(Wv + hg * 16 + i * 4);
        nw2[i*4+0] = -2.f * v4.x; nw2[i*4+1] = -2.f * v4.y;
        nw2[i*4+2] = -2.f * v4.z; nw2[i*4+3] = -2.f * v4.w;
        swv += v4.x + v4.y + v4.z + v4.w;
    }

    for (;;) {
        __syncthreads();    // protects curs AND sc/red reuse across items
        if (tid == 0) curs = (int)atomicAdd(qcnt, 1u);
        __syncthreads();
        const int idx = curs;
        if (idx >= NITEMS) break;          // uniform across block

        const int s  = idx >> 8;           // 0..7, always-active s=0 first
        const int t  = idx & 255;          // q-tile
        const int b  = t >> 5;
        const int k0 = s << 7;             // slice base (KCH=128)
        const int r0 = t * 8;              // global row base
        const int vl = vls[b];

        if (k0 >= vl) continue;            // fully masked: contributes nothing

        const int kcnt = min(vl - k0, KCH);
        const int nst  = (kcnt + 31) >> 5; // 1..4 k-steps of 32

        // Eq rows in registers: 4 rows x 16 h (per item)
        f16v eqr[4];
#pragma unroll
        for (int r = 0; r < 4; ++r) {
            const float4* p = (const float4*)(eqb + (size_t)(r0 + qg*4 + r) * HH + hg * 16);
            float4 x0 = p[0], x1 = p[1], x2 = p[2], x3 = p[3];
            f16v e;
            e[0]=x0.x;e[1]=x0.y;e[2]=x0.z;e[3]=x0.w; e[4]=x1.x;e[5]=x1.y;e[6]=x1.z;e[7]=x1.w;
            e[8]=x2.x;e[9]=x2.y;e[10]=x2.z;e[11]=x2.w; e[12]=x3.x;e[13]=x3.y;e[14]=x3.z;e[15]=x3.w;
            eqr[r] = e;
        }

        const float* ekbase = ekb + ((size_t)(b * NKV) + k0) * HH + hg * 16;

        auto loadEk = [&](f16v& e, int step) {
            const float4* p = (const float4*)(ekbase + (size_t)(step * 32 + ks) * HH);
            float4 x0 = p[0], x1 = p[1], x2 = p[2], x3 = p[3];
            e[0]=x0.x;e[1]=x0.y;e[2]=x0.z;e[3]=x0.w; e[4]=x1.x;e[5]=x1.y;e[6]=x1.z;e[7]=x1.w;
            e[8]=x2.x;e[9]=x2.y;e[10]=x2.z;e[11]=x2.w; e[12]=x3.x;e[13]=x3.y;e[14]=x3.z;e[15]=x3.w;
        };

        // score body with FUSED exp + mask: stores p = exp(score) or 0
        auto body = [&](const f16v& e, int step) {
            float a0 = swv, a1 = swv, a2 = swv, a3 = swv;
#pragma unroll
            for (int j = 0; j < 16; ++j) {
                float ej = e[j];
                float t0 = fmaf(eqr[0][j], ej, 1.0f);
                float t1 = fmaf(eqr[1][j], ej, 1.0f);
                float t2 = fmaf(eqr[2][j], ej, 1.0f);
                float t3 = fmaf(eqr[3][j], ej, 1.0f);
                float r0v = __builtin_amdgcn_rcpf(t0);
                float r1v = __builtin_amdgcn_rcpf(t1);
                float r2v = __builtin_amdgcn_rcpf(t2);
                float r3v = __builtin_amdgcn_rcpf(t3);
                float nj = nw2[j];
                a0 = fmaf(nj, r0v, a0);
                a1 = fmaf(nj, r1v, a1);
                a2 = fmaf(nj, r2v, a2);
                a3 = fmaf(nj, r3v, a3);
            }
            a0 += __shfl_xor(a0, 1); a0 += __shfl_xor(a0, 2); a0 += __shfl_xor(a0, 4);
            a1 += __shfl_xor(a1, 1); a1 += __shfl_xor(a1, 2); a1 += __shfl_xor(a1, 4);
            a2 += __shfl_xor(a2, 1); a2 += __shfl_xor(a2, 2); a2 += __shfl_xor(a2, 4);
            a3 += __shfl_xor(a3, 1); a3 += __shfl_xor(a3, 2); a3 += __shfl_xor(a3, 4);
            if (hg == 0) {
                int kk = step * 32 + ks;
                bool valid = (k0 + kk) < vl;
                sc[qg*4+0][kk] = valid ? __expf(a0) : 0.f;
                sc[qg*4+1][kk] = valid ? __expf(a1) : 0.f;
                sc[qg*4+2][kk] = valid ? __expf(a2) : 0.f;
                sc[qg*4+3][kk] = valid ? __expf(a3) : 0.f;
            }
        };

        // ---- score phase (2-deep register double-buffer) + tail zero-fill
        f16v ekA, ekB;
        loadEk(ekA, 0);
        for (int st = 0; st < nst; st += 2) {
            if (st + 1 < nst) loadEk(ekB, st + 1);
            body(ekA, st);
            if (st + 1 < nst) {
                if (st + 2 < nst) loadEk(ekA, st + 2);
                body(ekB, st + 1);
            }
        }
        // zero stale slots for steps never computed this item
        if (hg == 0) {
            for (int st = nst; st < (KCH >> 5); ++st) {
                int kk = st * 32 + ks;
                sc[qg*4+0][kk] = 0.f;
                sc[qg*4+1][kk] = 0.f;
                sc[qg*4+2][kk] = 0.f;
                sc[qg*4+3][kk] = 0.f;
            }
        }
        __syncthreads();

        // ---- row l-sums (no max needed): wave w owns row w
        {
            float sum = sc[w][lane] + sc[w][64 + lane];
#pragma unroll
            for (int off = 1; off < 64; off <<= 1) sum += __shfl_xor(sum, off);
            if (lane == 0) atomicAdd(&lsum[r0 + w], sum);
        }

        // ---- PV: wave w owns k in [w*16, w*16+16); accumulates ALL 8 rows
        float4 acc[8];
#pragma unroll
        for (int r = 0; r < 8; ++r) acc[r] = make_float4(0.f, 0.f, 0.f, 0.f);
        {
            const int kbase = w * 16;
            if (kbase < kcnt) {
                const float* vb = V + ((size_t)b * NKV + k0 + kbase) * DD + lane * 4;
                for (int kk = 0; kk < 16; kk += 4) {
                    float4 pr[8];
#pragma unroll
                    for (int r = 0; r < 8; ++r)
                        pr[r] = *(const float4*)&sc[r][kbase + kk];   // wave-uniform
#pragma unroll
                    for (int u = 0; u < 4; ++u) {
                        float4 vv = *(const float4*)(vb + (size_t)(kk + u) * DD);
#pragma unroll
                        for (int r = 0; r < 8; ++r) {
                            float p = (u == 0) ? pr[r].x : (u == 1) ? pr[r].y
                                    : (u == 2) ? pr[r].z : pr[r].w;
                            acc[r].x = fmaf(p, vv.x, acc[r].x);
                            acc[r].y = fmaf(p, vv.y, acc[r].y);
                            acc[r].z = fmaf(p, vv.z, acc[r].z);
                            acc[r].w = fmaf(p, vv.w, acc[r].w);
                        }
                    }
                }
            }
        }
        // 2-stage cross-wave reduction in LDS, then atomic merge into acc_out
        if (w < 4) {
#pragma unroll
            for (int r = 0; r < 8; ++r)
                *(float4*)&red[w][r][lane * 4] = acc[r];
        }
        __syncthreads();
        if (w >= 4) {
#pragma unroll
            for (int r = 0; r < 8; ++r) {
                float4 tv = *(const float4*)&red[w - 4][r][lane * 4];
                tv.x += acc[r].x; tv.y += acc[r].y;
                tv.z += acc[r].z; tv.w += acc[r].w;
                *(float4*)&red[w - 4][r][lane * 4] = tv;
            }
        }
        __syncthreads();
        {
            float4 o = {0.f, 0.f, 0.f, 0.f};
#pragma unroll
            for (int ss = 0; ss < 4; ++ss) {
                float4 tv = *(const float4*)&red[ss][w][lane * 4];
                o.x += tv.x; o.y += tv.y; o.z += tv.z; o.w += tv.w;
            }
            float* dst = acc_out + (size_t)(r0 + w) * DD + lane * 4;
            atomicAdd(dst + 0, o.x);
            atomicAdd(dst + 1, o.y);
            atomicAdd(dst + 2, o.z);
            atomicAdd(dst + 3, o.w);
        }
    }
}

// ---------------------------------------------------------------------------
// Kernel 3 v2: elementwise divide out = acc_out / lsum (4 MB traffic, ~3 us).
// ---------------------------------------------------------------------------
__global__ __launch_bounds__(256) void divide_kernel(
    const float* __restrict__ acc_out, const float* __restrict__ lsum,
    float* __restrict__ out)
{
    const int idx  = blockIdx.x * 256 + threadIdx.x;
    const int r    = idx >> 6;
    const int lane = idx & 63;
    float rinv = 1.0f / lsum[r];
    float4 a = *(const float4*)(acc_out + (size_t)r * DD + lane * 4);
    a.x *= rinv; a.y *= rinv; a.z *= rinv; a.w *= rinv;
    *(float4*)(out + (size_t)r * DD + lane * 4) = a;
}

// ---------------------------------------------------------------------------
extern "C" void kernel_launch(void* const* d_in, const int* in_sizes, int n_in,
                              void* d_out, int out_size, void* d_ws, size_t ws_size,
                              hipStream_t stream) {
    const float* Q   = (const float*)d_in[0];
    const float* K   = (const float*)d_in[1];
    const float* V   = (const float*)d_in[2];
    const int*   vls = (const int*)  d_in[3];
    const float* Wq  = (const float*)d_in[4];
    const float* Wk  = (const float*)d_in[5];
    const float* Wv  = (const float*)d_in[6];
    float* out = (float*)d_out;

    // ws layout: Eq 1 MB | Ek 4 MB | acc_out 2 MB | lsum 8 KB | qcnt 4 B
    float* eq  = (float*)d_ws;
    float* ek  = eq  + (size_t)BB * NQ * HH;
    float* acc = ek  + (size_t)BB * NKV * HH;
    float* ls  = acc + (size_t)BB * NQ * DD;
    unsigned int* qcnt = (unsigned int*)(ls + (size_t)BB * NQ);

    // zero accumulators + l-sums + queue counter (contiguous, one memset)
    hipMemsetAsync(acc, 0, ((size_t)BB * NQ * DD + BB * NQ) * sizeof(float) + sizeof(unsigned int), stream);
    proj_exp_kernel<<<(BB*NQ + BB*NKV) / 16, 256, 0, stream>>>(Q, K, Wq, Wk, eq, ek);
    attn_partial_kernel<<<NWORK, 512, 0, stream>>>(V, vls, Wv, eq, ek, acc, ls, qcnt);
    divide_kernel<<<BB * NQ / 4, 256, 0, stream>>>(acc, ls, out);
}